// Round 17
// baseline (325.964 us; speedup 1.0000x reference)
//
#include <hip/hip_runtime.h>
#include <hip/hip_fp16.h>
#include <math.h>

#define B_ 16
#define L_ 4096
#define H_ 8
#define E_ 64
#define C_ 512     // H*E
#define K_ 24
#define NT 256
#define RPAD 257      // padded row stride (float2 units) for the 16x256 LDS matrix
#define PSTRIDE 2052  // partial-spectrum row stride (float2), bins 0..2048 used
#define G_ 64         // channel groups (8 ch each) per batch for fft_bc

__device__ __forceinline__ float2 cmul(float2 a, float2 b) {
    return make_float2(a.x * b.x - a.y * b.y, a.x * b.y + a.y * b.x);
}
__device__ __forceinline__ float2 cadd(float2 a, float2 b) { return make_float2(a.x + b.x, a.y + b.y); }
__device__ __forceinline__ float2 csub(float2 a, float2 b) { return make_float2(a.x - b.x, a.y - b.y); }

// barrier that orders LDS only: does NOT drain vmcnt, so register prefetch
// loads stay in flight across it (no cross-thread global deps at these points)
__device__ __forceinline__ void bar_lds() {
    asm volatile("s_waitcnt lgkmcnt(0)" ::: "memory");
    __builtin_amdgcn_s_barrier();
}

// 16-point DIF FFT, natural-order input; output: X[k] = a[br4[k]]
__device__ __forceinline__ void fft16(float2 a[16]) {
    const float r2 = 0.70710678118654752f;
    const float c1 = 0.92387953251128676f;  // cos(pi/8)
    const float s1 = 0.38268343236508977f;  // sin(pi/8)
    const float2 W16[8] = {
        make_float2(1.f, 0.f),  make_float2(c1, -s1),  make_float2(r2, -r2),  make_float2(s1, -c1),
        make_float2(0.f, -1.f), make_float2(-s1, -c1), make_float2(-r2, -r2), make_float2(-c1, -s1)};
    #pragma unroll
    for (int j = 0; j < 8; ++j) {
        float2 u = a[j], v = a[j + 8];
        a[j]     = cadd(u, v);
        a[j + 8] = cmul(csub(u, v), W16[j]);
    }
    #pragma unroll
    for (int b = 0; b < 16; b += 8)
        #pragma unroll
        for (int j = 0; j < 4; ++j) {
            float2 u = a[b + j], v = a[b + j + 4];
            a[b + j]     = cadd(u, v);
            a[b + j + 4] = cmul(csub(u, v), W16[2 * j]);
        }
    #pragma unroll
    for (int b = 0; b < 16; b += 4)
        #pragma unroll
        for (int j = 0; j < 2; ++j) {
            float2 u = a[b + j], v = a[b + j + 2];
            a[b + j]     = cadd(u, v);
            a[b + j + 2] = cmul(csub(u, v), W16[4 * j]);
        }
    #pragma unroll
    for (int b = 0; b < 16; b += 2) {
        float2 u = a[b], v = a[b + 1];
        a[b]     = cadd(u, v);
        a[b + 1] = csub(u, v);
    }
}

// ---------------- fused transpose + FFT phase A (r13 structure, fp16 z output) ----------------
// At the chip's transpose ceiling (~3.1 TB/s, r13/r14). z stored fp16 ->
// round-trip halved. Writes full-64B-line efficient.
__global__ __launch_bounds__(256) void k_phaseA(const float* __restrict__ q,
                                                const float* __restrict__ k,
                                                __half2* __restrict__ z,
                                                int b0) {
    __shared__ float2 s2[256 * 17];   // [row = n1*16 + n2loc][ch], stride 17 -> 34.8 KB
    const int br4[16] = {0, 8, 4, 12, 2, 10, 6, 14, 1, 9, 5, 13, 3, 11, 7, 15};
    int w  = blockIdx.x;              // n2 window (16 of them)
    int g  = blockIdx.y;              // channel group of 16 (32 of them)
    int bl = blockIdx.z;
    int b  = b0 + bl;
    int tid = threadIdx.x;

    // ---- load 256 rows x 16 ch, float4 per (row, quad): 16 lines/wave-load ----
    const size_t base = (size_t)b * L_ * C_ + g * 16;
    int lrow = tid >> 2;              // 0..63
    int lq   = tid & 3;               // quad within 16 channels
    #pragma unroll
    for (int it = 0; it < 4; ++it) {
        int r   = lrow + (it << 6);                     // row = n1*16 + n2loc
        int tau = ((r >> 4) << 8) + (w << 4) + (r & 15);
        const float4 q4 = *(const float4*)(q + base + (size_t)tau * C_ + (lq << 2));
        const float4 k4 = *(const float4*)(k + base + (size_t)tau * C_ + (lq << 2));
        float2* dst = &s2[r * 17 + (lq << 2)];
        dst[0] = make_float2(q4.x, k4.x);
        dst[1] = make_float2(q4.y, k4.y);
        dst[2] = make_float2(q4.z, k4.z);
        dst[3] = make_float2(q4.w, k4.w);
    }
    __syncthreads();

    // ---- compute: thread = (ch = tid>>4, n2loc = tid&15) ----
    int ch = tid >> 4, n2loc = tid & 15;
    int n2 = (w << 4) + n2loc;
    float2 a[16];
    int rbase = n2loc * 17 + ch;
    #pragma unroll
    for (int n1 = 0; n1 < 16; ++n1) a[n1] = s2[n1 * 272 + rbase];
    fft16(a);
    // twiddle W4096^{n2*k1}: 4 independent chains stepped by w4 = W^{4*n2}
    float sn, cs;
    sincospif((float)n2 / 2048.0f, &sn, &cs);
    const float2 w1 = make_float2(cs, -sn);
    const float2 w2 = cmul(w1, w1);
    const float2 w4 = cmul(w2, w2);
    float2 tws[4] = {w1, w2, cmul(w2, w1), w4};
    __half2* zc = z + ((size_t)bl * C_ + (g * 16 + ch)) * L_ + n2;
    zc[0] = __float22half2_rn(a[0]);   // k1 = 0 (br4[0]=0, tw=1)
    #pragma unroll
    for (int k1 = 1; k1 < 16; ++k1) {
        int j = (k1 - 1) & 3;
        zc[(size_t)(k1 << 8)] = __float22half2_rn(cmul(a[br4[k1]], tws[j]));
        tws[j] = cmul(tws[j], w4);
    }
}

// ---------------- FFT phases B+C + cross-spectrum accumulate (half spectrum) ----------------
__global__ __launch_bounds__(256) void k_fft_bc(const __half2* __restrict__ z,
                                                float2* __restrict__ part,
                                                int b0) {
    __shared__ float2 s[16 * RPAD];
    __shared__ float2 tw256[256];     // tw256[r1*16+m2] = W256^{m2*r1}
    const int br4[16] = {0, 8, 4, 12, 2, 10, 6, 14, 1, 9, 5, 13, 3, 11, 7, 15};
    int t  = threadIdx.x;
    int bl = blockIdx.y;
    int b  = b0 + bl;
    int g  = blockIdx.x;              // channel group of 8
    int c0 = g * 8;

    {
        int r1 = t >> 4, m2 = t & 15;
        float sn, cs;
        sincospif((float)(r1 * m2) / 128.0f, &sn, &cs);
        tw256[t] = make_float2(cs, -sn);
    }
    float accx[8], accy[8], accN = 0.f;
    #pragma unroll
    for (int r = 0; r < 8; ++r) { accx[r] = 0.f; accy[r] = 0.f; }

    const int rowB = t >> 4, m2B = t & 15;
    const int k1C = t & 15, r1C = t >> 4;

    // prefetch channel 0 (stays in flight across the setup barrier)
    float2 a[16];
    {
        const __half2* zc0 = z + ((size_t)bl * C_ + c0) * L_;
        #pragma unroll
        for (int m1 = 0; m1 < 16; ++m1)
            a[m1] = __half22float2(zc0[(rowB << 8) + (m1 << 4) + m2B]);
    }
    bar_lds();   // tw256 ready

    for (int cc = 0; cc < 8; ++cc) {
        // ---- phase B (input prefetched in a[]) ----
        fft16(a);
        #pragma unroll
        for (int r1 = 0; r1 < 16; ++r1)
            s[rowB * RPAD + (r1 << 4) + m2B] = cmul(a[br4[r1]], tw256[(r1 << 4) + m2B]);
        bar_lds();
        // ---- phase C ----
        #pragma unroll
        for (int m2 = 0; m2 < 16; ++m2) a[m2] = s[k1C * RPAD + (r1C << 4) + m2];
        fft16(a);
        bar_lds();   // all threads' C-reads retired before col-stores overwrite s
        // ---- column store: X[r2*256+t] -> s[r2*RPAD + t] (conflict-free) ----
        #pragma unroll
        for (int r2 = 0; r2 < 16; ++r2)
            s[r2 * RPAD + t] = a[br4[r2]];
        // save self values the accumulate needs before prefetch clobbers a[]
        float2 sv[9];
        sv[0] = a[0];  sv[1] = a[8];  sv[2] = a[4];  sv[3] = a[12];
        sv[4] = a[2];  sv[5] = a[10]; sv[6] = a[6];  sv[7] = a[14];
        sv[8] = a[1];                 // bin 2048 holder (t==0 only uses it)
        // ---- prefetch next channel into now-dead a[] ----
        if (cc < 7) {
            const __half2* zn = z + ((size_t)bl * C_ + (c0 + cc + 1)) * L_;
            #pragma unroll
            for (int m1 = 0; m1 < 16; ++m1)
                a[m1] = __half22float2(zn[(rowB << 8) + (m1 << 4) + m2B]);
        }
        bar_lds();   // col-stores visible; prefetch stays in flight
        // ---- accumulate Q*conj(K): self from sv, partner from column 256-t ----
        #pragma unroll
        for (int r = 0; r < 8; ++r) {
            float2 A  = sv[r];                        // X[r*256 + t]
            float2 Bv = (t == 0) ? s[((16 - r) & 15) * RPAD]
                                 : s[(15 - r) * RPAD + (256 - t)];  // X[4096 - r*256 - t]
            float Qr = 0.5f * (A.x + Bv.x);
            float Qi = 0.5f * (A.y - Bv.y);
            float Kr = 0.5f * (A.y + Bv.y);
            float Ki = 0.5f * (A.x - Bv.x);
            accx[r] += Qr * Kr - Qi * Ki;
            accy[r] += Qr * Ki + Qi * Kr;
        }
        if (t == 0) accN += sv[8].x * sv[8].y;        // Nyquist: Q,K real there
        bar_lds();   // partner reads done before next phase B overwrites s
    }
    // ---- contention-free coalesced partial stores (no atomics) ----
    float2* pb = part + (size_t)(b * G_ + g) * PSTRIDE;
    #pragma unroll
    for (int r = 0; r < 8; ++r)
        pb[t + (r << 8)] = make_float2(accx[r], accy[r]);
    if (t == 0) pb[2048] = make_float2(accN, 0.f);
}

// ---------------- partial-spectrum reduction: cross[b][p] = sum_g part[b][g][p] ----------------
__global__ __launch_bounds__(256) void k_reduce(const float2* __restrict__ part,
                                                float* __restrict__ cross) {
    __shared__ float2 acc2[128];
    int b  = blockIdx.x;
    int pt = blockIdx.y;
    int t  = threadIdx.x;
    int pi = t & 127, gh = t >> 7;
    int p  = pt * 128 + pi;
    float sx = 0.f, sy = 0.f;
    if (p <= 2048) {
        const float2* base = part + ((size_t)b * G_ + gh * 32) * PSTRIDE + p;
        #pragma unroll 4
        for (int g = 0; g < 32; ++g) {
            float2 v = base[(size_t)g * PSTRIDE];
            sx += v.x; sy += v.y;
        }
    }
    if (gh == 1) acc2[pi] = make_float2(sx, sy);
    __syncthreads();
    if (gh == 0 && p <= 2048) {
        float2 o = acc2[pi];
        ((float2*)cross)[(size_t)b * L_ + p] = make_float2(sx + o.x, sy + o.y);
    }
}

// ---------------- inverse FFT via conj-forward 3-phase radix-16 ----------------
// cross holds only bins 0..2048; upper half reconstructed via S(L-p)=conj(S(p)).
__global__ __launch_bounds__(256) void k_ifft(const float* __restrict__ cross,
                                              float* __restrict__ mv) {
    __shared__ float2 s[16 * RPAD];
    __shared__ float2 tw256[256];
    const int br4[16] = {0, 8, 4, 12, 2, 10, 6, 14, 1, 9, 5, 13, 3, 11, 7, 15};
    int t = threadIdx.x;
    int b = blockIdx.x;
    {
        int r1 = t >> 4, m2 = t & 15;
        float sn, cs;
        sincospif((float)(r1 * m2) / 128.0f, &sn, &cs);
        tw256[t] = make_float2(cs, -sn);
    }
    const float2* cr = (const float2*)cross + (size_t)b * L_;
    float2 a[16];
    #pragma unroll
    for (int n1 = 0; n1 < 16; ++n1) {
        int P = (n1 << 8) + t;
        int hi = P > 2048;
        float2 v = cr[hi ? (L_ - P) : P];
        // want a = conj(S(P)): P<=2048 -> conj(v); P>2048 -> S(P)=conj(v) -> a = v
        a[n1] = hi ? v : make_float2(v.x, -v.y);
    }
    // ---- phase A ----
    fft16(a);
    {
        float sn, cs;
        sincospif((float)t / 2048.0f, &sn, &cs);
        const float2 w1 = make_float2(cs, -sn);
        float2 tw = w1;
        s[t] = a[0];
        #pragma unroll
        for (int k1 = 1; k1 < 16; ++k1) {
            s[k1 * RPAD + t] = cmul(a[br4[k1]], tw);
            tw = cmul(tw, w1);
        }
    }
    __syncthreads();
    // ---- phase B ----
    const int rowB = t >> 4, m2B = t & 15;
    #pragma unroll
    for (int m1 = 0; m1 < 16; ++m1) a[m1] = s[rowB * RPAD + (m1 << 4) + m2B];
    fft16(a);
    #pragma unroll
    for (int r1 = 0; r1 < 16; ++r1)
        s[rowB * RPAD + (r1 << 4) + m2B] = cmul(a[br4[r1]], tw256[(r1 << 4) + m2B]);
    __syncthreads();
    // ---- phase C: write mv directly (k = r2*256 + t, coalesced) ----
    const int k1C = t & 15, r1C = t >> 4;
    #pragma unroll
    for (int m2 = 0; m2 < 16; ++m2) a[m2] = s[k1C * RPAD + (r1C << 4) + m2];
    fft16(a);
    const float scale = 1.0f / ((float)L_ * (float)C_);
    #pragma unroll
    for (int r2 = 0; r2 < 16; ++r2)
        mv[(size_t)b * L_ + (r2 << 8) + t] = a[br4[r2]].x * scale;
}

// ---------------- top-24 + per-batch softmax (register-resident, wave-shuffle) ----------------
__global__ __launch_bounds__(256) void k_topk(const float* __restrict__ mv,
                                              int* __restrict__ idx,
                                              float* __restrict__ wts) {
    __shared__ float wv[4];
    __shared__ int   wi[4];
    __shared__ int   idxL[K_];
    int tid = threadIdx.x;
    float vloc[16];
    #pragma unroll
    for (int r = 0; r < 16; ++r) {
        int tt = tid + (r << 8);
        float ssum = 0.f;
        for (int b = 0; b < B_; ++b) ssum += mv[(size_t)b * L_ + tt];
        vloc[r] = ssum;
    }
    int lane = tid & 63, w = tid >> 6;
    for (int i = 0; i < K_; ++i) {
        float best = -INFINITY; int bi = 1 << 30;
        #pragma unroll
        for (int r = 0; r < 16; ++r) {
            float v = vloc[r]; int ii = tid + (r << 8);
            if (v > best || (v == best && ii < bi)) { best = v; bi = ii; }
        }
        #pragma unroll
        for (int off = 32; off > 0; off >>= 1) {
            float ov = __shfl_down(best, off);
            int   oi = __shfl_down(bi, off);
            if (ov > best || (ov == best && oi < bi)) { best = ov; bi = oi; }
        }
        if (lane == 0) { wv[w] = best; wi[w] = bi; }
        __syncthreads();
        if (tid == 0) {
            float bb = wv[0]; int bj = wi[0];
            for (int j = 1; j < 4; ++j)
                if (wv[j] > bb || (wv[j] == bb && wi[j] < bj)) { bb = wv[j]; bj = wi[j]; }
            idxL[i] = bj; idx[i] = bj;
        }
        __syncthreads();
        int win = idxL[i];
        #pragma unroll
        for (int r = 0; r < 16; ++r)
            if (win == tid + (r << 8)) vloc[r] = -INFINITY;
    }
    if (tid < B_) {
        int b = tid;
        float ww[K_]; float wm = -INFINITY;
        for (int i = 0; i < K_; ++i) { ww[i] = mv[(size_t)b * L_ + idxL[i]]; wm = fmaxf(wm, ww[i]); }
        float ssum = 0.f;
        for (int i = 0; i < K_; ++i) { ww[i] = expf(ww[i] - wm); ssum += ww[i]; }
        float inv = 1.f / ssum;
        for (int i = 0; i < K_; ++i) wts[b * K_ + i] = ww[i] * inv;
    }
}

// ---------------- 24-tap circulant gather-sum, persistent fp16 LDS tau-ring ----------------
// r16 post-mortem: 4 blocks/CU raised occupancy 19->33% and VALU 24->42%, but
// dur stayed 114us because WRITE ballooned 133->220MB: partial-line (16B per
// 2KB-strided row) writes only merge in L2 when all 8 sibling blocks (adjacent
// wk, same XCD) are time-aligned; with 2048 blocks > 1024 resident the second
// launch wave is ragged -> dirty partial lines evicted before completion.
// Fix: persistent 1024 blocks (= exact residency at 4 blocks/CU), each block
// runs TWO synchronized passes (wk = xcd*256 + p*128 + id>>3). All 8 siblings
// of every output line are co-resident and phase-aligned -> lines complete in
// L2 before eviction.
__global__ __launch_bounds__(256) void k_agg(const float* __restrict__ vals,
                                             const int* __restrict__ idx,
                                             const float* __restrict__ wts,
                                             float* __restrict__ out) {
    __shared__ __half2 sv2[L_][2];  // 32 KB ring: tau x 4ch fp16 -> 4 blocks/CU
    __shared__ int   di[K_];
    __shared__ float dw[K_];
    const int tid = threadIdx.x;
    const int id  = blockIdx.x;     // 0..1023

    #pragma unroll
    for (int p = 0; p < 2; ++p) {
        // bijective: wk = xcd*256 + p*128 + (id>>3); siblings (adjacent wk,
        // same line) differ by id+-8 -> same xcd, co-resident.
        int wk = ((id & 7) << 8) | (p << 7) | (id >> 3);
        int b  = wk >> 7;              // 0..15 (xcd*2 + p)
        int c0 = (wk & 127) << 2;      // channel-quad start

        if (p) __syncthreads();        // pass-0 LDS reads done before restage
        if (tid < K_) { di[tid] = idx[tid]; dw[tid] = wts[b * K_ + tid]; }

        // ---- stage: two 8-deep reg batches (32 VGPR), cvt to fp16, LDS write ----
        const float* gbase = vals + (size_t)b * L_ * C_ + c0;
        #pragma unroll
        for (int sr = 0; sr < 2; ++sr) {
            float4 xv[8];
            #pragma unroll
            for (int it = 0; it < 8; ++it) {
                int tau = (((sr << 3) + it) << 8) + tid;
                xv[it] = *(const float4*)(gbase + (size_t)tau * C_);
            }
            #pragma unroll
            for (int it = 0; it < 8; ++it) {
                int tau = (((sr << 3) + it) << 8) + tid;
                sv2[tau][0] = __float22half2_rn(make_float2(xv[it].x, xv[it].y));
                sv2[tau][1] = __float22half2_rn(make_float2(xv[it].z, xv[it].w));
            }
        }
        __syncthreads();

        // taps/weights to registers (fully-unrolled static indexing)
        int   dir[K_]; float dwr[K_];
        #pragma unroll
        for (int i = 0; i < K_; ++i) { dir[i] = di[i]; dwr[i] = dw[i]; }

        float* obase = out + (size_t)b * L_ * C_ + c0;
        for (int r = 0; r < 16; ++r) {
            int tau = (r << 8) + tid;
            float4 acc = make_float4(0.f, 0.f, 0.f, 0.f);
            #pragma unroll
            for (int i = 0; i < K_; ++i) {
                int row = (tau + dir[i]) & (L_ - 1);
                float2 x0 = __half22float2(sv2[row][0]);
                float2 x1 = __half22float2(sv2[row][1]);
                float w = dwr[i];
                acc.x = fmaf(w, x0.x, acc.x);
                acc.y = fmaf(w, x0.y, acc.y);
                acc.z = fmaf(w, x1.x, acc.z);
                acc.w = fmaf(w, x1.y, acc.w);
            }
            *(float4*)(obase + (size_t)tau * C_) = acc;
        }
    }
}

extern "C" void kernel_launch(void* const* d_in, const int* in_sizes, int n_in,
                              void* d_out, int out_size, void* d_ws, size_t ws_size,
                              hipStream_t stream) {
    const float* q = (const float*)d_in[0];
    const float* k = (const float*)d_in[1];
    const float* v = (const float*)d_in[2];
    float* out = (float*)d_out;
    char* ws = (char*)d_ws;

    // ws layout: [cross 512KB | mv 256KB | idx | wts | part at 2MB (16.8MB) | z at 20MB (fp16)]
    float*   cross = (float*)ws;
    float*   mv    = (float*)(ws + (1 << 20));
    int*     idx   = (int*)(ws + (1 << 20) + (1 << 18));
    float*   wts   = (float*)(ws + (1 << 20) + (1 << 18) + 4096);
    float2*  part  = (float2*)(ws + (2 << 20));
    __half2* z     = (__half2*)(ws + (size_t)(20 << 20));

    size_t zcap = (ws_size > (size_t)(20 << 20)) ? ws_size - (size_t)(20 << 20) : 0;
    int P = 16;
    while (P > 1 && (size_t)P * C_ * L_ * sizeof(__half2) > zcap) P >>= 1;
    // P=8 chunking: z chunk (64MB fp16) stays L3-resident for fft_bc reads.
    if (P > 8) P = 8;

    for (int b0 = 0; b0 < B_; b0 += P) {
        dim3 g1(16, 32, P);   // n2 windows x ch groups x batches
        k_phaseA<<<g1, 256, 0, stream>>>(q, k, z, b0);
        dim3 g2(G_, P);
        k_fft_bc<<<g2, 256, 0, stream>>>(z, part, b0);
    }
    dim3 gr(B_, 17);
    k_reduce<<<gr, 256, 0, stream>>>(part, cross);
    k_ifft<<<B_, 256, 0, stream>>>(cross, mv);
    k_topk<<<1, 256, 0, stream>>>(mv, idx, wts);
    k_agg<<<1024, 256, 0, stream>>>(v, idx, wts, out);
}

// Round 18
// 309.464 us; speedup vs baseline: 1.0533x; 1.0533x over previous
//
#include <hip/hip_runtime.h>
#include <hip/hip_fp16.h>
#include <math.h>

#define B_ 16
#define L_ 4096
#define H_ 8
#define E_ 64
#define C_ 512     // H*E
#define K_ 24
#define NT 256
#define RPAD 257      // padded row stride (float2 units) for the 16x256 LDS matrix
#define PSTRIDE 2052  // partial-spectrum row stride (float2), bins 0..2048 used
#define G_ 64         // channel groups (8 ch each) per batch for fft_bc

__device__ __forceinline__ float2 cmul(float2 a, float2 b) {
    return make_float2(a.x * b.x - a.y * b.y, a.x * b.y + a.y * b.x);
}
__device__ __forceinline__ float2 cadd(float2 a, float2 b) { return make_float2(a.x + b.x, a.y + b.y); }
__device__ __forceinline__ float2 csub(float2 a, float2 b) { return make_float2(a.x - b.x, a.y - b.y); }

// barrier that orders LDS only: does NOT drain vmcnt, so register prefetch
// loads stay in flight across it (no cross-thread global deps at these points)
__device__ __forceinline__ void bar_lds() {
    asm volatile("s_waitcnt lgkmcnt(0)" ::: "memory");
    __builtin_amdgcn_s_barrier();
}

// 16-point DIF FFT, natural-order input; output: X[k] = a[br4[k]]
__device__ __forceinline__ void fft16(float2 a[16]) {
    const float r2 = 0.70710678118654752f;
    const float c1 = 0.92387953251128676f;  // cos(pi/8)
    const float s1 = 0.38268343236508977f;  // sin(pi/8)
    const float2 W16[8] = {
        make_float2(1.f, 0.f),  make_float2(c1, -s1),  make_float2(r2, -r2),  make_float2(s1, -c1),
        make_float2(0.f, -1.f), make_float2(-s1, -c1), make_float2(-r2, -r2), make_float2(-c1, -s1)};
    #pragma unroll
    for (int j = 0; j < 8; ++j) {
        float2 u = a[j], v = a[j + 8];
        a[j]     = cadd(u, v);
        a[j + 8] = cmul(csub(u, v), W16[j]);
    }
    #pragma unroll
    for (int b = 0; b < 16; b += 8)
        #pragma unroll
        for (int j = 0; j < 4; ++j) {
            float2 u = a[b + j], v = a[b + j + 4];
            a[b + j]     = cadd(u, v);
            a[b + j + 4] = cmul(csub(u, v), W16[2 * j]);
        }
    #pragma unroll
    for (int b = 0; b < 16; b += 4)
        #pragma unroll
        for (int j = 0; j < 2; ++j) {
            float2 u = a[b + j], v = a[b + j + 2];
            a[b + j]     = cadd(u, v);
            a[b + j + 2] = cmul(csub(u, v), W16[4 * j]);
        }
    #pragma unroll
    for (int b = 0; b < 16; b += 2) {
        float2 u = a[b], v = a[b + 1];
        a[b]     = cadd(u, v);
        a[b + 1] = csub(u, v);
    }
}

// ---------------- fused transpose + FFT phase A (r13 structure, fp16 z output) ----------------
// At the chip's transpose ceiling (~3.1 TB/s, r13/r14). z stored fp16 ->
// round-trip halved. Writes full-64B-line efficient.
__global__ __launch_bounds__(256) void k_phaseA(const float* __restrict__ q,
                                                const float* __restrict__ k,
                                                __half2* __restrict__ z,
                                                int b0) {
    __shared__ float2 s2[256 * 17];   // [row = n1*16 + n2loc][ch], stride 17 -> 34.8 KB
    const int br4[16] = {0, 8, 4, 12, 2, 10, 6, 14, 1, 9, 5, 13, 3, 11, 7, 15};
    int w  = blockIdx.x;              // n2 window (16 of them)
    int g  = blockIdx.y;              // channel group of 16 (32 of them)
    int bl = blockIdx.z;
    int b  = b0 + bl;
    int tid = threadIdx.x;

    // ---- load 256 rows x 16 ch, float4 per (row, quad): 16 lines/wave-load ----
    const size_t base = (size_t)b * L_ * C_ + g * 16;
    int lrow = tid >> 2;              // 0..63
    int lq   = tid & 3;               // quad within 16 channels
    #pragma unroll
    for (int it = 0; it < 4; ++it) {
        int r   = lrow + (it << 6);                     // row = n1*16 + n2loc
        int tau = ((r >> 4) << 8) + (w << 4) + (r & 15);
        const float4 q4 = *(const float4*)(q + base + (size_t)tau * C_ + (lq << 2));
        const float4 k4 = *(const float4*)(k + base + (size_t)tau * C_ + (lq << 2));
        float2* dst = &s2[r * 17 + (lq << 2)];
        dst[0] = make_float2(q4.x, k4.x);
        dst[1] = make_float2(q4.y, k4.y);
        dst[2] = make_float2(q4.z, k4.z);
        dst[3] = make_float2(q4.w, k4.w);
    }
    __syncthreads();

    // ---- compute: thread = (ch = tid>>4, n2loc = tid&15) ----
    int ch = tid >> 4, n2loc = tid & 15;
    int n2 = (w << 4) + n2loc;
    float2 a[16];
    int rbase = n2loc * 17 + ch;
    #pragma unroll
    for (int n1 = 0; n1 < 16; ++n1) a[n1] = s2[n1 * 272 + rbase];
    fft16(a);
    // twiddle W4096^{n2*k1}: 4 independent chains stepped by w4 = W^{4*n2}
    float sn, cs;
    sincospif((float)n2 / 2048.0f, &sn, &cs);
    const float2 w1 = make_float2(cs, -sn);
    const float2 w2 = cmul(w1, w1);
    const float2 w4 = cmul(w2, w2);
    float2 tws[4] = {w1, w2, cmul(w2, w1), w4};
    __half2* zc = z + ((size_t)bl * C_ + (g * 16 + ch)) * L_ + n2;
    zc[0] = __float22half2_rn(a[0]);   // k1 = 0 (br4[0]=0, tw=1)
    #pragma unroll
    for (int k1 = 1; k1 < 16; ++k1) {
        int j = (k1 - 1) & 3;
        zc[(size_t)(k1 << 8)] = __float22half2_rn(cmul(a[br4[k1]], tws[j]));
        tws[j] = cmul(tws[j], w4);
    }
}

// ---------------- FFT phases B+C + cross-spectrum accumulate (half spectrum) ----------------
__global__ __launch_bounds__(256) void k_fft_bc(const __half2* __restrict__ z,
                                                float2* __restrict__ part,
                                                int b0) {
    __shared__ float2 s[16 * RPAD];
    __shared__ float2 tw256[256];     // tw256[r1*16+m2] = W256^{m2*r1}
    const int br4[16] = {0, 8, 4, 12, 2, 10, 6, 14, 1, 9, 5, 13, 3, 11, 7, 15};
    int t  = threadIdx.x;
    int bl = blockIdx.y;
    int b  = b0 + bl;
    int g  = blockIdx.x;              // channel group of 8
    int c0 = g * 8;

    {
        int r1 = t >> 4, m2 = t & 15;
        float sn, cs;
        sincospif((float)(r1 * m2) / 128.0f, &sn, &cs);
        tw256[t] = make_float2(cs, -sn);
    }
    float accx[8], accy[8], accN = 0.f;
    #pragma unroll
    for (int r = 0; r < 8; ++r) { accx[r] = 0.f; accy[r] = 0.f; }

    const int rowB = t >> 4, m2B = t & 15;
    const int k1C = t & 15, r1C = t >> 4;

    // prefetch channel 0 (stays in flight across the setup barrier)
    float2 a[16];
    {
        const __half2* zc0 = z + ((size_t)bl * C_ + c0) * L_;
        #pragma unroll
        for (int m1 = 0; m1 < 16; ++m1)
            a[m1] = __half22float2(zc0[(rowB << 8) + (m1 << 4) + m2B]);
    }
    bar_lds();   // tw256 ready

    for (int cc = 0; cc < 8; ++cc) {
        // ---- phase B (input prefetched in a[]) ----
        fft16(a);
        #pragma unroll
        for (int r1 = 0; r1 < 16; ++r1)
            s[rowB * RPAD + (r1 << 4) + m2B] = cmul(a[br4[r1]], tw256[(r1 << 4) + m2B]);
        bar_lds();
        // ---- phase C ----
        #pragma unroll
        for (int m2 = 0; m2 < 16; ++m2) a[m2] = s[k1C * RPAD + (r1C << 4) + m2];
        fft16(a);
        bar_lds();   // all threads' C-reads retired before col-stores overwrite s
        // ---- column store: X[r2*256+t] -> s[r2*RPAD + t] (conflict-free) ----
        #pragma unroll
        for (int r2 = 0; r2 < 16; ++r2)
            s[r2 * RPAD + t] = a[br4[r2]];
        // save self values the accumulate needs before prefetch clobbers a[]
        float2 sv[9];
        sv[0] = a[0];  sv[1] = a[8];  sv[2] = a[4];  sv[3] = a[12];
        sv[4] = a[2];  sv[5] = a[10]; sv[6] = a[6];  sv[7] = a[14];
        sv[8] = a[1];                 // bin 2048 holder (t==0 only uses it)
        // ---- prefetch next channel into now-dead a[] ----
        if (cc < 7) {
            const __half2* zn = z + ((size_t)bl * C_ + (c0 + cc + 1)) * L_;
            #pragma unroll
            for (int m1 = 0; m1 < 16; ++m1)
                a[m1] = __half22float2(zn[(rowB << 8) + (m1 << 4) + m2B]);
        }
        bar_lds();   // col-stores visible; prefetch stays in flight
        // ---- accumulate Q*conj(K): self from sv, partner from column 256-t ----
        #pragma unroll
        for (int r = 0; r < 8; ++r) {
            float2 A  = sv[r];                        // X[r*256 + t]
            float2 Bv = (t == 0) ? s[((16 - r) & 15) * RPAD]
                                 : s[(15 - r) * RPAD + (256 - t)];  // X[4096 - r*256 - t]
            float Qr = 0.5f * (A.x + Bv.x);
            float Qi = 0.5f * (A.y - Bv.y);
            float Kr = 0.5f * (A.y + Bv.y);
            float Ki = 0.5f * (A.x - Bv.x);
            accx[r] += Qr * Kr - Qi * Ki;
            accy[r] += Qr * Ki + Qi * Kr;
        }
        if (t == 0) accN += sv[8].x * sv[8].y;        // Nyquist: Q,K real there
        bar_lds();   // partner reads done before next phase B overwrites s
    }
    // ---- contention-free coalesced partial stores (no atomics) ----
    float2* pb = part + (size_t)(b * G_ + g) * PSTRIDE;
    #pragma unroll
    for (int r = 0; r < 8; ++r)
        pb[t + (r << 8)] = make_float2(accx[r], accy[r]);
    if (t == 0) pb[2048] = make_float2(accN, 0.f);
}

// ---------------- partial-spectrum reduction: cross[b][p] = sum_g part[b][g][p] ----------------
__global__ __launch_bounds__(256) void k_reduce(const float2* __restrict__ part,
                                                float* __restrict__ cross) {
    __shared__ float2 acc2[128];
    int b  = blockIdx.x;
    int pt = blockIdx.y;
    int t  = threadIdx.x;
    int pi = t & 127, gh = t >> 7;
    int p  = pt * 128 + pi;
    float sx = 0.f, sy = 0.f;
    if (p <= 2048) {
        const float2* base = part + ((size_t)b * G_ + gh * 32) * PSTRIDE + p;
        #pragma unroll 4
        for (int g = 0; g < 32; ++g) {
            float2 v = base[(size_t)g * PSTRIDE];
            sx += v.x; sy += v.y;
        }
    }
    if (gh == 1) acc2[pi] = make_float2(sx, sy);
    __syncthreads();
    if (gh == 0 && p <= 2048) {
        float2 o = acc2[pi];
        ((float2*)cross)[(size_t)b * L_ + p] = make_float2(sx + o.x, sy + o.y);
    }
}

// ---------------- inverse FFT via conj-forward 3-phase radix-16 ----------------
// cross holds only bins 0..2048; upper half reconstructed via S(L-p)=conj(S(p)).
__global__ __launch_bounds__(256) void k_ifft(const float* __restrict__ cross,
                                              float* __restrict__ mv) {
    __shared__ float2 s[16 * RPAD];
    __shared__ float2 tw256[256];
    const int br4[16] = {0, 8, 4, 12, 2, 10, 6, 14, 1, 9, 5, 13, 3, 11, 7, 15};
    int t = threadIdx.x;
    int b = blockIdx.x;
    {
        int r1 = t >> 4, m2 = t & 15;
        float sn, cs;
        sincospif((float)(r1 * m2) / 128.0f, &sn, &cs);
        tw256[t] = make_float2(cs, -sn);
    }
    const float2* cr = (const float2*)cross + (size_t)b * L_;
    float2 a[16];
    #pragma unroll
    for (int n1 = 0; n1 < 16; ++n1) {
        int P = (n1 << 8) + t;
        int hi = P > 2048;
        float2 v = cr[hi ? (L_ - P) : P];
        // want a = conj(S(P)): P<=2048 -> conj(v); P>2048 -> S(P)=conj(v) -> a = v
        a[n1] = hi ? v : make_float2(v.x, -v.y);
    }
    // ---- phase A ----
    fft16(a);
    {
        float sn, cs;
        sincospif((float)t / 2048.0f, &sn, &cs);
        const float2 w1 = make_float2(cs, -sn);
        float2 tw = w1;
        s[t] = a[0];
        #pragma unroll
        for (int k1 = 1; k1 < 16; ++k1) {
            s[k1 * RPAD + t] = cmul(a[br4[k1]], tw);
            tw = cmul(tw, w1);
        }
    }
    __syncthreads();
    // ---- phase B ----
    const int rowB = t >> 4, m2B = t & 15;
    #pragma unroll
    for (int m1 = 0; m1 < 16; ++m1) a[m1] = s[rowB * RPAD + (m1 << 4) + m2B];
    fft16(a);
    #pragma unroll
    for (int r1 = 0; r1 < 16; ++r1)
        s[rowB * RPAD + (r1 << 4) + m2B] = cmul(a[br4[r1]], tw256[(r1 << 4) + m2B]);
    __syncthreads();
    // ---- phase C: write mv directly (k = r2*256 + t, coalesced) ----
    const int k1C = t & 15, r1C = t >> 4;
    #pragma unroll
    for (int m2 = 0; m2 < 16; ++m2) a[m2] = s[k1C * RPAD + (r1C << 4) + m2];
    fft16(a);
    const float scale = 1.0f / ((float)L_ * (float)C_);
    #pragma unroll
    for (int r2 = 0; r2 < 16; ++r2)
        mv[(size_t)b * L_ + (r2 << 8) + t] = a[br4[r2]].x * scale;
}

// ---------------- top-24 + per-batch softmax (register-resident, wave-shuffle) ----------------
__global__ __launch_bounds__(256) void k_topk(const float* __restrict__ mv,
                                              int* __restrict__ idx,
                                              float* __restrict__ wts) {
    __shared__ float wv[4];
    __shared__ int   wi[4];
    __shared__ int   idxL[K_];
    int tid = threadIdx.x;
    float vloc[16];
    #pragma unroll
    for (int r = 0; r < 16; ++r) {
        int tt = tid + (r << 8);
        float ssum = 0.f;
        for (int b = 0; b < B_; ++b) ssum += mv[(size_t)b * L_ + tt];
        vloc[r] = ssum;
    }
    int lane = tid & 63, w = tid >> 6;
    for (int i = 0; i < K_; ++i) {
        float best = -INFINITY; int bi = 1 << 30;
        #pragma unroll
        for (int r = 0; r < 16; ++r) {
            float v = vloc[r]; int ii = tid + (r << 8);
            if (v > best || (v == best && ii < bi)) { best = v; bi = ii; }
        }
        #pragma unroll
        for (int off = 32; off > 0; off >>= 1) {
            float ov = __shfl_down(best, off);
            int   oi = __shfl_down(bi, off);
            if (ov > best || (ov == best && oi < bi)) { best = ov; bi = oi; }
        }
        if (lane == 0) { wv[w] = best; wi[w] = bi; }
        __syncthreads();
        if (tid == 0) {
            float bb = wv[0]; int bj = wi[0];
            for (int j = 1; j < 4; ++j)
                if (wv[j] > bb || (wv[j] == bb && wi[j] < bj)) { bb = wv[j]; bj = wi[j]; }
            idxL[i] = bj; idx[i] = bj;
        }
        __syncthreads();
        int win = idxL[i];
        #pragma unroll
        for (int r = 0; r < 16; ++r)
            if (win == tid + (r << 8)) vloc[r] = -INFINITY;
    }
    if (tid < B_) {
        int b = tid;
        float ww[K_]; float wm = -INFINITY;
        for (int i = 0; i < K_; ++i) { ww[i] = mv[(size_t)b * L_ + idxL[i]]; wm = fmaxf(wm, ww[i]); }
        float ssum = 0.f;
        for (int i = 0; i < K_; ++i) { ww[i] = expf(ww[i] - wm); ssum += ww[i]; }
        float inv = 1.f / ssum;
        for (int i = 0; i < K_; ++i) wts[b * K_ + i] = ww[i] * inv;
    }
}

// ---------------- 24-tap circulant gather-sum, fp16 LDS tau-ring (r16 best: 114us) ----------------
// r17 lesson: persistent 2-pass alignment cut WRITE 220->155MB but serialized
// staging behind compute (no cross-block overlap) -> net -16us. Revert to the
// 2048-block r16 form; accept the ~1.6x partial-line write amplification (the
// full fix needs 32-ch blocks -> 256KB ring > LDS; structurally unavailable).
// Micro-fix vs r16: the two adjacent half2 reads per tap merge into ONE
// ds_read_b64 (float2 reinterpret) -> 192 instead of 384 LDS reads/thread.
__global__ __launch_bounds__(256) void k_agg(const float* __restrict__ vals,
                                             const int* __restrict__ idx,
                                             const float* __restrict__ wts,
                                             float* __restrict__ out) {
    __shared__ __half2 sv2[L_][2];  // 32 KB ring: tau x 4ch fp16 -> 4 blocks/CU
    __shared__ int   di[K_];
    __shared__ float dw[K_];
    const int tid = threadIdx.x;
    // XCD-aware bijective decode: 2048 blocks; xcd = id&7 owns 2 whole batches
    int id = blockIdx.x;
    int wk = ((id & 7) << 8) | (id >> 3);
    int b  = wk >> 7;              // 0..15
    int c0 = (wk & 127) << 2;      // channel-quad start

    if (tid < K_) { di[tid] = idx[tid]; dw[tid] = wts[b * K_ + tid]; }

    // ---- stage: two 8-deep reg batches (32 VGPR), cvt to fp16, LDS write ----
    const float* gbase = vals + (size_t)b * L_ * C_ + c0;
    #pragma unroll
    for (int sr = 0; sr < 2; ++sr) {
        float4 xv[8];
        #pragma unroll
        for (int it = 0; it < 8; ++it) {
            int tau = (((sr << 3) + it) << 8) + tid;
            xv[it] = *(const float4*)(gbase + (size_t)tau * C_);
        }
        #pragma unroll
        for (int it = 0; it < 8; ++it) {
            int tau = (((sr << 3) + it) << 8) + tid;
            sv2[tau][0] = __float22half2_rn(make_float2(xv[it].x, xv[it].y));
            sv2[tau][1] = __float22half2_rn(make_float2(xv[it].z, xv[it].w));
        }
    }
    __syncthreads();

    // taps/weights to registers (fully-unrolled static indexing)
    int   dir[K_]; float dwr[K_];
    #pragma unroll
    for (int i = 0; i < K_; ++i) { dir[i] = di[i]; dwr[i] = dw[i]; }

    float* obase = out + (size_t)b * L_ * C_ + c0;
    for (int r = 0; r < 16; ++r) {
        int tau = (r << 8) + tid;
        float4 acc = make_float4(0.f, 0.f, 0.f, 0.f);
        #pragma unroll
        for (int i = 0; i < K_; ++i) {
            int row = (tau + dir[i]) & (L_ - 1);
            float2 pair = *reinterpret_cast<const float2*>(&sv2[row][0]);  // ds_read_b64
            __half2 h0 = *reinterpret_cast<__half2*>(&pair.x);
            __half2 h1 = *reinterpret_cast<__half2*>(&pair.y);
            float2 x0 = __half22float2(h0);
            float2 x1 = __half22float2(h1);
            float w = dwr[i];
            acc.x = fmaf(w, x0.x, acc.x);
            acc.y = fmaf(w, x0.y, acc.y);
            acc.z = fmaf(w, x1.x, acc.z);
            acc.w = fmaf(w, x1.y, acc.w);
        }
        *(float4*)(obase + (size_t)tau * C_) = acc;
    }
}

extern "C" void kernel_launch(void* const* d_in, const int* in_sizes, int n_in,
                              void* d_out, int out_size, void* d_ws, size_t ws_size,
                              hipStream_t stream) {
    const float* q = (const float*)d_in[0];
    const float* k = (const float*)d_in[1];
    const float* v = (const float*)d_in[2];
    float* out = (float*)d_out;
    char* ws = (char*)d_ws;

    // ws layout: [cross 512KB | mv 256KB | idx | wts | part at 2MB (16.8MB) | z at 20MB (fp16)]
    float*   cross = (float*)ws;
    float*   mv    = (float*)(ws + (1 << 20));
    int*     idx   = (int*)(ws + (1 << 20) + (1 << 18));
    float*   wts   = (float*)(ws + (1 << 20) + (1 << 18) + 4096);
    float2*  part  = (float2*)(ws + (2 << 20));
    __half2* z     = (__half2*)(ws + (size_t)(20 << 20));

    size_t zcap = (ws_size > (size_t)(20 << 20)) ? ws_size - (size_t)(20 << 20) : 0;
    int P = 16;
    while (P > 1 && (size_t)P * C_ * L_ * sizeof(__half2) > zcap) P >>= 1;
    // P=8 chunking: z chunk (64MB fp16) stays L3-resident for fft_bc reads.
    if (P > 8) P = 8;

    for (int b0 = 0; b0 < B_; b0 += P) {
        dim3 g1(16, 32, P);   // n2 windows x ch groups x batches
        k_phaseA<<<g1, 256, 0, stream>>>(q, k, z, b0);
        dim3 g2(G_, P);
        k_fft_bc<<<g2, 256, 0, stream>>>(z, part, b0);
    }
    dim3 gr(B_, 17);
    k_reduce<<<gr, 256, 0, stream>>>(part, cross);
    k_ifft<<<B_, 256, 0, stream>>>(cross, mv);
    k_topk<<<1, 256, 0, stream>>>(mv, idx, wts);
    k_agg<<<2048, 256, 0, stream>>>(v, idx, wts, out);
}